// Round 5
// baseline (122.041 us; speedup 1.0000x reference)
//
#include <hip/hip_runtime.h>

// ContrastiveLoss on MI355X (gfx950), B=8192, D=128, labels in [0,2048).
// loss = -(1/cnt) sum_{i: P_i>0} [ S_i/P_i - M - ln Z_i ]
//   Z_i = sum_{j != i} exp(sim_ij - M),  sim = E E^T / T,  M = 1/T (valid shift).
//   S_i = (e_i . g_{lab_i} - e_i . e_i) / T  with fp32 class sums g_c.
//   P_i = count[lab_i] - 1.
// R16: R15 counters (main 45.8us, MfmaUtil 6.9%, VALU 13.5%, FETCH 8MB,
//      occupancy grid-limited) showed main is a serial chain of L2-miss
//      stalls: each load->wait->compute group eats ~900cy on its slowest
//      line, and the block's 4 waves read IDENTICAL B data (no stall
//      diversity). Two mechanism-aligned fixes, rest frozen:
//      (a) register ping-pong prefetch distance 2 in the nt loop — issue
//          LOADB(nt+2) before consuming tile nt, so miss latency overlaps
//          the previous tile's MFMA+exp instead of serializing;
//      (b) XCD-aware bijective swizzle (1056 = 8*132) — each XCD gets a
//          contiguous tt-run, its 4MB L2 warms the 2MB Ebf once (T1).
// Kept from R15: no B-staging (direct L2 loads, 16 whole 64B lines/instr),
//      zpartR not pre-zeroed (finalize masks lane >= r>>8), separate
//      finalize2 (R14: per-block device fence cost ~9us), plain
//      __launch_bounds__(256) (R3/R7/R10: min-waves pin causes spill).

#define BATCH 8192
#define DIMK  128
#define INV_T 14.285714285714286f
#define MSUB  14.285714285714286f
#define K1    20.609929155311264f   // INV_T * log2(e)
#define K2    20.609929155311264f   // MSUB  * log2(e)

typedef short bf16x8 __attribute__((ext_vector_type(8)));
typedef float f32x4  __attribute__((ext_vector_type(4)));

__device__ __forceinline__ unsigned short f2bf_rne(float f) {
    unsigned u = __float_as_uint(f);
    u += 0x7FFFu + ((u >> 16) & 1u);
    return (unsigned short)(u >> 16);
}
__device__ __forceinline__ float bf2f(unsigned short b) {
    return __uint_as_float(((unsigned)b) << 16);
}

// ---------------------------------------------------------------------------
// Prep: blocks [0,1024): fp32->bf16 cvt (4 elems/thread) + zero zcol (32 KB).
//       blocks [1024,1536): class sums, 1 class per wave, labels staged in LDS.
__global__ __launch_bounds__(256) void
prep_kernel(const float* __restrict__ emb, const int* __restrict__ labels,
            ushort* __restrict__ Ebf, float* __restrict__ gsum, int* __restrict__ gcnt,
            float4* __restrict__ zcol4) {
    if (blockIdx.x < 1024) {
        int i = blockIdx.x * 256 + threadIdx.x;
        if (i < 2048) {                       // zcol: 8192 floats = 2048 float4
            float4 z = {0.f, 0.f, 0.f, 0.f};
            zcol4[i] = z;
        }
        float4 v = ((const float4*)emb)[i];
        ushort4 o;
        o.x = f2bf_rne(v.x); o.y = f2bf_rne(v.y);
        o.z = f2bf_rne(v.z); o.w = f2bf_rne(v.w);
        ((ushort4*)Ebf)[i] = o;
    } else {
        __shared__ int labs[BATCH];           // 32 KB
        const int tid = threadIdx.x;
#pragma unroll
        for (int it = 0; it < 8; ++it)
            ((int4*)labs)[it * 256 + tid] = ((const int4*)labels)[it * 256 + tid];
        __syncthreads();

        const int lane = tid & 63;
        const int wid  = tid >> 6;
        const int c    = (blockIdx.x - 1024) * 4 + wid;   // class id [0,2048)
        float2 acc = {0.f, 0.f};
        int cnt = 0;
        int nl = labs[lane];
        for (int j0 = 0; j0 < BATCH; j0 += 64) {
            int cur = nl;
            int nidx = j0 + 64 < BATCH ? j0 + 64 : 0;
            nl = labs[nidx + lane];
            unsigned long long m = __ballot(cur == c);
            cnt += __popcll(m);
            while (m) {
                int j = __ffsll(m) - 1;
                m &= m - 1;
                float2 v = *(const float2*)(emb + (size_t)(j0 + j) * DIMK + lane * 2);
                acc.x += v.x; acc.y += v.y;
            }
        }
        *(float2*)(gsum + (size_t)c * DIMK + lane * 2) = acc;
        if (lane == 0) gcnt[c] = cnt;
    }
}

// ---------------------------------------------------------------------------
// Main: Z partials over the upper triangle. Grid 1056 = 528 macro-tiles x 2
// row-halves, block 256 (4 waves). Swizzled tt: each XCD owns a contiguous
// run of 132 tiles (L2 locality). Macro-tile (ti,tj), tj>=ti; this block
// covers rows [ti*256 + half*128, +128) x cols [tj*256, +256).
// B fragments load DIRECT from Ebf (L2-resident) with ping-pong register
// prefetch (distance 2): LOADB(nt+2) issues before COMPUTE(nt) consumes,
// so L2/L3-miss latency overlaps the previous tile's MFMA+exp work.
// Wave owns 32 rows (afrag[2][4]=32 VGPRs).
// Row partials -> zpartR[tj][row] (plain stores). Col partials (off-diag
// only) -> cpart LDS combine -> atomicAdd zcol[col] (~16 adds/address).
__global__ __launch_bounds__(256) void
contrastive_main(const ushort* __restrict__ Ebf, float* __restrict__ zpartR,
                 float* __restrict__ zcol) {
    __shared__ float cpart[4][256];                   // 4 KB (only LDS)
    const int tid  = threadIdx.x;
    const int lane = tid & 63;
    const int wid  = tid >> 6;
    const int quad = lane >> 4;
    const int l16  = lane & 15;

    // XCD-aware bijective swizzle: 1056 = 8 * 132. blockIdx round-robins
    // XCDs, so (bid&7) == XCD; give it contiguous tt in [x*132, x*132+132).
    const int bid = blockIdx.x;
    const int tt  = (bid & 7) * 132 + (bid >> 3);

    // tt -> (ti, tj, half)
    int b = tt >> 1;
    const int half = tt & 1;
    int ti = 0;
    while (b >= 32 - ti) { b -= 32 - ti; ++ti; }
    const int tj = ti + b;
    const int row_base = ti * 256 + half * 128 + wid * 32;

    // A-fragments for this wave's 32 rows (register-resident), from L2.
    bf16x8 afrag[2][4];
#pragma unroll
    for (int mt = 0; mt < 2; ++mt)
#pragma unroll
        for (int kk = 0; kk < 4; ++kk)
            afrag[mt][kk] = *(const bf16x8*)(Ebf + (size_t)(row_base + mt * 16 + l16) * DIMK
                                             + kk * 32 + quad * 8);

    float zacc[8];
#pragma unroll
    for (int s = 0; s < 8; ++s) zacc[s] = 0.f;

    // Lane-invariant B base: col = tj*256 + nt*16 + l16, k-chunk = kk*4+quad.
    // Per load instruction the wave covers 16 whole 64B lines (4 lanes/line).
    const ushort* bbase = Ebf + (size_t)(tj * 256 + l16) * DIMK + quad * 8;

#define LOADB(dst, nt)                                                        \
    {                                                                         \
        _Pragma("unroll")                                                     \
        for (int kk = 0; kk < 4; ++kk)                                        \
            dst[kk] = *(const bf16x8*)(bbase + (nt) * (16 * DIMK) + kk * 32); \
    }

#define COMPUTE(bf, nt)                                                       \
    {                                                                         \
        float csum = 0.f;                                                     \
        _Pragma("unroll")                                                     \
        for (int mt = 0; mt < 2; ++mt) {                                      \
            f32x4 c = {0.f, 0.f, 0.f, 0.f};                                   \
            _Pragma("unroll")                                                 \
            for (int kk = 0; kk < 4; ++kk)                                    \
                c = __builtin_amdgcn_mfma_f32_16x16x32_bf16(afrag[mt][kk], bf[kk], c, 0, 0, 0); \
            _Pragma("unroll")                                                 \
            for (int r = 0; r < 4; ++r) {                                     \
                float e = __builtin_amdgcn_exp2f(__builtin_fmaf(c[r], K1, -K2)); \
                zacc[mt * 4 + r] += e;                                        \
                csum += e;                                                    \
            }                                                                 \
        }                                                                     \
        csum += __shfl_xor(csum, 16, 64);                                     \
        csum += __shfl_xor(csum, 32, 64);                                     \
        if (quad == 0) cpart[wid][(nt) * 16 + l16] = csum;                    \
    }

    // Ping-pong prefetch, distance 2: each COMPUTE consumes a group issued
    // two compute-bodies earlier; 4-8 loads always in flight per wave.
    bf16x8 bA[4], bB[4];
    LOADB(bA, 0);
    LOADB(bB, 1);
#pragma unroll
    for (int nt = 0; nt < 16; nt += 2) {
        COMPUTE(bA, nt);
        if (nt + 2 < 16) LOADB(bA, nt + 2);
        COMPUTE(bB, nt + 1);
        if (nt + 3 < 16) LOADB(bB, nt + 3);
    }

#undef LOADB
#undef COMPUTE

    // Row partials: reduce each row-slot over the 16 lanes sharing the row.
#pragma unroll
    for (int s = 0; s < 8; ++s) {
        float z = zacc[s];
#pragma unroll
        for (int m = 1; m <= 8; m <<= 1) z += __shfl_xor(z, m, 64);
        if (l16 == 0) {
            int row = row_base + (s >> 2) * 16 + quad * 4 + (s & 3);
            zpartR[(size_t)tj * BATCH + row] = z;
        }
    }

    // Col partials: combine the 4 waves, one distributed atomic per column.
    __syncthreads();
    if (ti != tj) {
        float s = cpart[0][tid] + cpart[1][tid] + cpart[2][tid] + cpart[3][tid];
        atomicAdd(&zcol[tj * 256 + tid], s);
    }
}

// ---------------------------------------------------------------------------
// Finalize 1: 512 blocks x 256 (4 waves); each wave processes 4 rows.
// Per row: lane l covers dims 2l,2l+1; lanes 0..31 read zpartR, lane 32 zcol.
// zpartR is only written for tj >= (r>>8): mask the gather (no pre-zeroing).
__global__ __launch_bounds__(256) void
finalize1(const float* __restrict__ emb, const ushort* __restrict__ Ebf,
          const int* __restrict__ labels, const float* __restrict__ gsum,
          const int* __restrict__ gcnt, const float* __restrict__ zpartR,
          const float* __restrict__ zcol,
          float* __restrict__ bpart, int* __restrict__ bcnt) {
    __shared__ float sf[4];
    __shared__ int   si[4];
    const int lane = threadIdx.x & 63;
    const int wid  = threadIdx.x >> 6;

    float wsum = 0.f;
    int   wcnt = 0;
#pragma unroll
    for (int it = 0; it < 4; ++it) {
        const int r   = blockIdx.x * 16 + wid * 4 + it;
        const int lab = labels[r];
        const int P   = gcnt[lab] - 1;
        const int tp  = r >> 8;               // row's macro-tile

        float2 ev = *(const float2*)(emb  + (size_t)r   * DIMK + lane * 2);
        float2 gv = *(const float2*)(gsum + (size_t)lab * DIMK + lane * 2);
        unsigned bb = *(const unsigned*)(Ebf + (size_t)r * DIMK + lane * 2);
        float b0 = bf2f((unsigned short)(bb & 0xFFFF));
        float b1 = bf2f((unsigned short)(bb >> 16));

        float dotg = ev.x * gv.x + ev.y * gv.y;
        float ssd  = ev.x * ev.x + ev.y * ev.y;
        float sdbf = b0 * b0 + b1 * b1;
        float Z = 0.f;
        if (lane < 32) {
            if (lane >= tp) Z = zpartR[(size_t)lane * BATCH + r];
        } else if (lane == 32) {
            Z = zcol[r];
        }

#pragma unroll
        for (int m = 1; m <= 32; m <<= 1) {
            dotg += __shfl_xor(dotg, m, 64);
            ssd  += __shfl_xor(ssd,  m, 64);
            sdbf += __shfl_xor(sdbf, m, 64);
            Z    += __shfl_xor(Z,    m, 64);
        }
        Z -= __builtin_amdgcn_exp2f(__builtin_fmaf(sdbf, K1, -K2));  // remove diagonal

        const bool has = (P > 0);
        wsum += has ? ((dotg - ssd) * INV_T / (float)P - MSUB - __logf(Z)) : 0.f;
        wcnt += has ? 1 : 0;
    }

    if (lane == 0) { sf[wid] = wsum; si[wid] = wcnt; }
    __syncthreads();
    if (threadIdx.x == 0) {
        bpart[blockIdx.x] = sf[0] + sf[1] + sf[2] + sf[3];
        bcnt [blockIdx.x] = si[0] + si[1] + si[2] + si[3];
    }
}

// ---------------------------------------------------------------------------
// Finalize 2: reduce 512 block partials -> scalar loss. 1 block x 256.
__global__ __launch_bounds__(256) void
finalize2(const float* __restrict__ bpart, const int* __restrict__ bcnt,
          float* __restrict__ out) {
    __shared__ float sf[4];
    __shared__ int   si[4];
    const int t = threadIdx.x;
    float v = 0.f; int c = 0;
#pragma unroll
    for (int k = 0; k < 2; ++k) {
        v += bpart[t + k * 256];
        c += bcnt [t + k * 256];
    }
#pragma unroll
    for (int m = 1; m <= 32; m <<= 1) {
        v += __shfl_xor(v, m, 64);
        c += __shfl_xor(c, m, 64);
    }
    if ((t & 63) == 0) { sf[t >> 6] = v; si[t >> 6] = c; }
    __syncthreads();
    if (t == 0) {
        float tot = sf[0] + sf[1] + sf[2] + sf[3];
        int cc = si[0] + si[1] + si[2] + si[3];
        out[0] = -tot / (float)(cc > 0 ? cc : 1);
    }
}

extern "C" void kernel_launch(void* const* d_in, const int* in_sizes, int n_in,
                              void* d_out, int out_size, void* d_ws, size_t ws_size,
                              hipStream_t stream) {
    const float* emb  = (const float*)d_in[0];
    const int* labels = (const int*)d_in[1];
    float* out        = (float*)d_out;

    char* ws = (char*)d_ws;
    ushort* Ebf    = (ushort*)ws;                         // 2 MB  (8192*128*2)
    float*  zpartR = (float*)(ws + (2u << 20));           // 1 MB  (32*8192*4)
    float*  zcol   = (float*)(ws + (3u << 20));           // 32 KB (8192*4)
    float*  gsum   = (float*)(ws + (4u << 20));           // 1 MB  (2048*128*4)
    int*    gcnt   = (int*)  (ws + (5u << 20));           // 8 KB
    float*  bpart  = (float*)(ws + (5u << 20) + 8192);    // 8 KB
    int*    bcnt   = (int*)  (ws + (5u << 20) + 16384);   // 8 KB

    prep_kernel<<<1536, 256, 0, stream>>>(emb, labels, Ebf, gsum, gcnt,
                                          (float4*)zcol);
    contrastive_main<<<1056, 256, 0, stream>>>(Ebf, zpartR, zcol);
    finalize1<<<512, 256, 0, stream>>>(emb, Ebf, labels, gsum, gcnt, zpartR, zcol,
                                       bpart, bcnt);
    finalize2<<<1, 256, 0, stream>>>(bpart, bcnt, out);
}

// Round 6
// 96.649 us; speedup vs baseline: 1.2627x; 1.2627x over previous
//
#include <hip/hip_runtime.h>

// ContrastiveLoss on MI355X (gfx950), B=8192, D=128, labels in [0,2048).
// loss = -(1/cnt) sum_{i: P_i>0} [ S_i/P_i - M - ln Z_i ]
//   Z_i = sum_{j != i} exp(sim_ij - M),  sim = E E^T / T,  M = 1/T (valid shift).
//   S_i = (e_i . g_{lab_i} - e_i . e_i) / T  with fp32 class sums g_c.
//   P_i = count[lab_i] - 1.
// R17: occupancy round. Cross-round ledger: main is latency-bound everywhere
//      (MfmaUtil ~7%, VALU ~13%, HBM ~2%, conflicts 0); R14->R15 isolated
//      "remove LDS staging" as +16us (staging IS right: 4x intra-block reuse
//      at 120cy LDS beats scattered 200-900cy L2); R16 isolated "prefetch
//      regs" as occupancy-negative (VGPR 40->100, occ 33.7->15.9%). All
//      variants ran <=16.5 of 32 waves/CU. So: keep the verified R11 tile
//      body EXACTLY (staged B, XOR layout w/ measured 0 conflicts, 16x16x32
//      MFMA, same fragments) and repackage as 512-thread 8-wave blocks:
//      256 rows x 128 cols per block, grid still 1056 (528 macro x 2
//      col-halves). LDS 36KB -> 4 blocks/CU -> 32 waves/CU (100%) vs 16.5.
//      Barriers per block 4 -> 2. zpartR becomes [64][8192] (tj2=tj*2+ch);
//      finalize gathers 64 lanes and adds zcol after the butterfly.
// Kept: plain launch_bounds (R3/R7/R10: min-waves pin spills), separate
//      finalize2 (R14: device-fence ticket cost ~9us), no zpartR pre-zero
//      (finalize masks lane >= 2*tp), no XCD swizzle (R16: unproven here).

#define BATCH 8192
#define DIMK  128
#define INV_T 14.285714285714286f
#define MSUB  14.285714285714286f
#define K1    20.609929155311264f   // INV_T * log2(e)
#define K2    20.609929155311264f   // MSUB  * log2(e)

typedef short bf16x8 __attribute__((ext_vector_type(8)));
typedef float f32x4  __attribute__((ext_vector_type(4)));

__device__ __forceinline__ unsigned short f2bf_rne(float f) {
    unsigned u = __float_as_uint(f);
    u += 0x7FFFu + ((u >> 16) & 1u);
    return (unsigned short)(u >> 16);
}
__device__ __forceinline__ float bf2f(unsigned short b) {
    return __uint_as_float(((unsigned)b) << 16);
}

// ---------------------------------------------------------------------------
// Prep: blocks [0,1024): fp32->bf16 cvt (4 elems/thread) + zero zcol (32 KB).
//       blocks [1024,1536): class sums, 1 class per wave, labels staged in LDS.
__global__ __launch_bounds__(256) void
prep_kernel(const float* __restrict__ emb, const int* __restrict__ labels,
            ushort* __restrict__ Ebf, float* __restrict__ gsum, int* __restrict__ gcnt,
            float4* __restrict__ zcol4) {
    if (blockIdx.x < 1024) {
        int i = blockIdx.x * 256 + threadIdx.x;
        if (i < 2048) {                       // zcol: 8192 floats = 2048 float4
            float4 z = {0.f, 0.f, 0.f, 0.f};
            zcol4[i] = z;
        }
        float4 v = ((const float4*)emb)[i];
        ushort4 o;
        o.x = f2bf_rne(v.x); o.y = f2bf_rne(v.y);
        o.z = f2bf_rne(v.z); o.w = f2bf_rne(v.w);
        ((ushort4*)Ebf)[i] = o;
    } else {
        __shared__ int labs[BATCH];           // 32 KB
        const int tid = threadIdx.x;
#pragma unroll
        for (int it = 0; it < 8; ++it)
            ((int4*)labs)[it * 256 + tid] = ((const int4*)labels)[it * 256 + tid];
        __syncthreads();

        const int lane = tid & 63;
        const int wid  = tid >> 6;
        const int c    = (blockIdx.x - 1024) * 4 + wid;   // class id [0,2048)
        float2 acc = {0.f, 0.f};
        int cnt = 0;
        int nl = labs[lane];
        for (int j0 = 0; j0 < BATCH; j0 += 64) {
            int cur = nl;
            int nidx = j0 + 64 < BATCH ? j0 + 64 : 0;
            nl = labs[nidx + lane];
            unsigned long long m = __ballot(cur == c);
            cnt += __popcll(m);
            while (m) {
                int j = __ffsll(m) - 1;
                m &= m - 1;
                float2 v = *(const float2*)(emb + (size_t)(j0 + j) * DIMK + lane * 2);
                acc.x += v.x; acc.y += v.y;
            }
        }
        *(float2*)(gsum + (size_t)c * DIMK + lane * 2) = acc;
        if (lane == 0) gcnt[c] = cnt;
    }
}

// ---------------------------------------------------------------------------
// Main: Z partials over the upper triangle. Grid 1056 = 528 macro-tiles x 2
// col-halves; block 512 (8 waves). Macro-tile (ti,tj), tj>=ti; this block
// covers rows [ti*256, +256) x cols [tj*256 + ch*128, +128).
// B staged once (32 KB), conflict-free XOR layout (measured 0 conflicts):
//   chunk (col, c) -> 16B-unit (col>>4)*256 + c*16 + ((col&15)^c).
// Wave owns 32 rows (afrag[2][4] = 32 VGPRs); 8 nt-tiles of 16 cols.
// 2 barriers per block (post-staging, pre-cpart-combine).
// Row partials -> zpartR[tj2][row], tj2 = tj*2+ch. Col partials (off-diag
// only) -> cpart LDS combine -> atomicAdd zcol[col].
__global__ __launch_bounds__(512) void
contrastive_main(const ushort* __restrict__ Ebf, float* __restrict__ zpartR,
                 float* __restrict__ zcol) {
    __shared__ __align__(16) ushort Bs[2048 * 8];     // 32 KB (2048 16B units)
    __shared__ float cpart[8][128];                   // 4 KB
    const int tid  = threadIdx.x;
    const int lane = tid & 63;
    const int wid  = tid >> 6;                        // 0..7
    const int quad = lane >> 4;
    const int l16  = lane & 15;

    // block -> (ti, tj, ch)
    int b = blockIdx.x >> 1;
    const int ch = blockIdx.x & 1;
    int ti = 0;
    while (b >= 32 - ti) { b -= 32 - ti; ++ti; }
    const int tj  = ti + b;
    const int tj2 = tj * 2 + ch;
    const int row_base = ti * 256 + wid * 32;
    const int col_base = tj * 256 + ch * 128;

    // A-fragments for this wave's 32 rows (register-resident), from L2.
    bf16x8 afrag[2][4];
#pragma unroll
    for (int mt = 0; mt < 2; ++mt)
#pragma unroll
        for (int kk = 0; kk < 4; ++kk)
            afrag[mt][kk] = *(const bf16x8*)(Ebf + (size_t)(row_base + mt * 16 + l16) * DIMK
                                             + kk * 32 + quad * 8);

    // Stage 128 cols: 2048 16B chunks; thread t handles chunk f = it*512+t:
    // col = f>>4, c = f&15; global read coalesced (16 lanes = 256B of one col);
    // LDS write at swizzled unit (col>>4)*256 + c*16 + ((col&15)^c).
#pragma unroll
    for (int it = 0; it < 4; ++it) {
        int f   = it * 512 + tid;
        int col = f >> 4;
        int c   = f & 15;
        uint4 v = *(const uint4*)(Ebf + (size_t)(col_base + col) * DIMK + c * 8);
        *(uint4*)&Bs[((col >> 4) * 256 + c * 16 + ((col & 15) ^ c)) * 8] = v;
    }
    __syncthreads();

    float zacc[8];
#pragma unroll
    for (int s = 0; s < 8; ++s) zacc[s] = 0.f;

    for (int nt = 0; nt < 8; ++nt) {
        bf16x8 bfrag[4];
#pragma unroll
        for (int kk = 0; kk < 4; ++kk) {
            const int c2 = kk * 4 + quad;
            bfrag[kk] = *(const bf16x8*)&Bs[(nt * 256 + c2 * 16 + (l16 ^ c2)) * 8];
        }

        float csum = 0.f;
#pragma unroll
        for (int mt = 0; mt < 2; ++mt) {
            f32x4 c = {0.f, 0.f, 0.f, 0.f};
#pragma unroll
            for (int kk = 0; kk < 4; ++kk)
                c = __builtin_amdgcn_mfma_f32_16x16x32_bf16(afrag[mt][kk], bfrag[kk], c, 0, 0, 0);
#pragma unroll
            for (int r = 0; r < 4; ++r) {
                float e = __builtin_amdgcn_exp2f(__builtin_fmaf(c[r], K1, -K2));
                zacc[mt * 4 + r] += e;
                csum += e;
            }
        }
        // col partial for col (nt*16 + l16) over this wave's 32 rows
        csum += __shfl_xor(csum, 16, 64);
        csum += __shfl_xor(csum, 32, 64);
        if (quad == 0) cpart[wid][nt * 16 + l16] = csum;
    }

    // Row partials: reduce each row-slot over the 16 lanes sharing the row.
#pragma unroll
    for (int s = 0; s < 8; ++s) {
        float z = zacc[s];
#pragma unroll
        for (int m = 1; m <= 8; m <<= 1) z += __shfl_xor(z, m, 64);
        if (l16 == 0) {
            int row = row_base + (s >> 2) * 16 + quad * 4 + (s & 3);
            zpartR[(size_t)tj2 * BATCH + row] = z;
        }
    }

    // Col partials: combine the 8 waves, one distributed atomic per column.
    __syncthreads();
    if (ti != tj && tid < 128) {
        float s = cpart[0][tid] + cpart[1][tid] + cpart[2][tid] + cpart[3][tid]
                + cpart[4][tid] + cpart[5][tid] + cpart[6][tid] + cpart[7][tid];
        atomicAdd(&zcol[col_base + tid], s);
    }
}

// ---------------------------------------------------------------------------
// Finalize 1: 512 blocks x 256 (4 waves); each wave processes 4 rows.
// Per row: lane l covers dims 2l,2l+1; all 64 lanes gather zpartR[tj2][r]
// (written only for tj2 >= 2*(r>>8): mask, no pre-zeroing); zcol[r] added
// after the butterfly (broadcast load, same value on all lanes).
__global__ __launch_bounds__(256) void
finalize1(const float* __restrict__ emb, const ushort* __restrict__ Ebf,
          const int* __restrict__ labels, const float* __restrict__ gsum,
          const int* __restrict__ gcnt, const float* __restrict__ zpartR,
          const float* __restrict__ zcol,
          float* __restrict__ bpart, int* __restrict__ bcnt) {
    __shared__ float sf[4];
    __shared__ int   si[4];
    const int lane = threadIdx.x & 63;
    const int wid  = threadIdx.x >> 6;

    float wsum = 0.f;
    int   wcnt = 0;
#pragma unroll
    for (int it = 0; it < 4; ++it) {
        const int r   = blockIdx.x * 16 + wid * 4 + it;
        const int lab = labels[r];
        const int P   = gcnt[lab] - 1;
        const int tp2 = (r >> 8) * 2;         // first valid tj2 for this row

        float2 ev = *(const float2*)(emb  + (size_t)r   * DIMK + lane * 2);
        float2 gv = *(const float2*)(gsum + (size_t)lab * DIMK + lane * 2);
        unsigned bb = *(const unsigned*)(Ebf + (size_t)r * DIMK + lane * 2);
        float b0 = bf2f((unsigned short)(bb & 0xFFFF));
        float b1 = bf2f((unsigned short)(bb >> 16));

        float dotg = ev.x * gv.x + ev.y * gv.y;
        float ssd  = ev.x * ev.x + ev.y * ev.y;
        float sdbf = b0 * b0 + b1 * b1;
        float Z = 0.f;
        if (lane >= tp2) Z = zpartR[(size_t)lane * BATCH + r];

#pragma unroll
        for (int m = 1; m <= 32; m <<= 1) {
            dotg += __shfl_xor(dotg, m, 64);
            ssd  += __shfl_xor(ssd,  m, 64);
            sdbf += __shfl_xor(sdbf, m, 64);
            Z    += __shfl_xor(Z,    m, 64);
        }
        Z += zcol[r];                                                // below-diag cols
        Z -= __builtin_amdgcn_exp2f(__builtin_fmaf(sdbf, K1, -K2));  // remove diagonal

        const bool has = (P > 0);
        wsum += has ? ((dotg - ssd) * INV_T / (float)P - MSUB - __logf(Z)) : 0.f;
        wcnt += has ? 1 : 0;
    }

    if (lane == 0) { sf[wid] = wsum; si[wid] = wcnt; }
    __syncthreads();
    if (threadIdx.x == 0) {
        bpart[blockIdx.x] = sf[0] + sf[1] + sf[2] + sf[3];
        bcnt [blockIdx.x] = si[0] + si[1] + si[2] + si[3];
    }
}

// ---------------------------------------------------------------------------
// Finalize 2: reduce 512 block partials -> scalar loss. 1 block x 256.
__global__ __launch_bounds__(256) void
finalize2(const float* __restrict__ bpart, const int* __restrict__ bcnt,
          float* __restrict__ out) {
    __shared__ float sf[4];
    __shared__ int   si[4];
    const int t = threadIdx.x;
    float v = 0.f; int c = 0;
#pragma unroll
    for (int k = 0; k < 2; ++k) {
        v += bpart[t + k * 256];
        c += bcnt [t + k * 256];
    }
#pragma unroll
    for (int m = 1; m <= 32; m <<= 1) {
        v += __shfl_xor(v, m, 64);
        c += __shfl_xor(c, m, 64);
    }
    if ((t & 63) == 0) { sf[t >> 6] = v; si[t >> 6] = c; }
    __syncthreads();
    if (t == 0) {
        float tot = sf[0] + sf[1] + sf[2] + sf[3];
        int cc = si[0] + si[1] + si[2] + si[3];
        out[0] = -tot / (float)(cc > 0 ? cc : 1);
    }
}

extern "C" void kernel_launch(void* const* d_in, const int* in_sizes, int n_in,
                              void* d_out, int out_size, void* d_ws, size_t ws_size,
                              hipStream_t stream) {
    const float* emb  = (const float*)d_in[0];
    const int* labels = (const int*)d_in[1];
    float* out        = (float*)d_out;

    char* ws = (char*)d_ws;
    ushort* Ebf    = (ushort*)ws;                         // 2 MB  (8192*128*2)
    float*  zpartR = (float*)(ws + (2u << 20));           // 2 MB  (64*8192*4)
    float*  zcol   = (float*)(ws + (4u << 20));           // 32 KB (8192*4)
    float*  gsum   = (float*)(ws + (5u << 20));           // 1 MB  (2048*128*4)
    int*    gcnt   = (int*)  (ws + (6u << 20));           // 8 KB
    float*  bpart  = (float*)(ws + (6u << 20) + 8192);    // 8 KB
    int*    bcnt   = (int*)  (ws + (6u << 20) + 16384);   // 8 KB

    prep_kernel<<<1536, 256, 0, stream>>>(emb, labels, Ebf, gsum, gcnt,
                                          (float4*)zcol);
    contrastive_main<<<1056, 512, 0, stream>>>(Ebf, zpartR, zcol);
    finalize1<<<512, 256, 0, stream>>>(emb, Ebf, labels, gsum, gcnt, zpartR, zcol,
                                       bpart, bcnt);
    finalize2<<<1, 256, 0, stream>>>(bpart, bcnt, out);
}

// Round 7
// 93.279 us; speedup vs baseline: 1.3083x; 1.0361x over previous
//
#include <hip/hip_runtime.h>

// ContrastiveLoss on MI355X (gfx950), B=8192, D=128, labels in [0,2048).
// loss = -(1/cnt) sum_{i: P_i>0} [ S_i/P_i - M - ln Z_i ]
//   Z_i = sum_{j != i} exp(sim_ij - M),  sim = E E^T / T,  M = 1/T (valid shift).
//   S_i = (e_i . g_{lab_i} - e_i . e_i) / T  with fp32 class sums g_c.
//   P_i = count[lab_i] - 1.
// R18: R17 (8-wave 256x128 blocks, 96.6us, best) + three non-main levers:
//      (a) XCD-aware bijective swizzle on main's 1056 tile blocks (1056=8*132;
//          R16 verified FETCH 8->6MB, this time without the occupancy-killing
//          prefetch regs);
//      (b) class-sum fused into main as blocks [1056,1312) (8 classes/block,
//          labs aliases the Bs LDS region) — prep shrinks to 1024 convert
//          blocks, class-sums overlap main's tile window; fin1 (the gsum
//          consumer) still launches after main completes;
//      (c) zpartR transposed to [row][tj2]: fin1's Z gather becomes 256B
//          contiguous per row (4 lines vs 64 TA-serialized lines). Main's
//          write side is scattered-4B either way. Cross-block same-line
//          writes are split-K-standard (distinct bytes + kernel boundary).
// Frozen: R17 tile body (staged B, XOR LDS layout w/ measured 0 conflicts,
//      16x16x32 MFMA), plain launch_bounds (R3/R7/R10), separate finalize2
//      (R14: ticket fence cost ~9us), no zpartR pre-zero (fin1 masks
//      lane >= 2*(r>>8)).

#define BATCH 8192
#define DIMK  128
#define INV_T 14.285714285714286f
#define MSUB  14.285714285714286f
#define K1    20.609929155311264f   // INV_T * log2(e)
#define K2    20.609929155311264f   // MSUB  * log2(e)

typedef short bf16x8 __attribute__((ext_vector_type(8)));
typedef float f32x4  __attribute__((ext_vector_type(4)));

__device__ __forceinline__ unsigned short f2bf_rne(float f) {
    unsigned u = __float_as_uint(f);
    u += 0x7FFFu + ((u >> 16) & 1u);
    return (unsigned short)(u >> 16);
}
__device__ __forceinline__ float bf2f(unsigned short b) {
    return __uint_as_float(((unsigned)b) << 16);
}

// ---------------------------------------------------------------------------
// Prep: 1024 blocks: fp32->bf16 cvt (4 elems/thread) + zero zcol (32 KB).
__global__ __launch_bounds__(256) void
prep_kernel(const float* __restrict__ emb, ushort* __restrict__ Ebf,
            float4* __restrict__ zcol4) {
    int i = blockIdx.x * 256 + threadIdx.x;
    if (i < 2048) {                           // zcol: 8192 floats = 2048 float4
        float4 z = {0.f, 0.f, 0.f, 0.f};
        zcol4[i] = z;
    }
    float4 v = ((const float4*)emb)[i];
    ushort4 o;
    o.x = f2bf_rne(v.x); o.y = f2bf_rne(v.y);
    o.z = f2bf_rne(v.z); o.w = f2bf_rne(v.w);
    ((ushort4*)Ebf)[i] = o;
}

// ---------------------------------------------------------------------------
// Main: blocks [0,1056): Z partials over the upper triangle; blocks
// [1056,1312): class sums (8 classes/block, overlapping the tile tail).
// Tile blocks: grid 1056 = 528 macro-tiles x 2 col-halves, 512 threads
// (8 waves), XCD-swizzled (each XCD gets a contiguous run of 132 tt).
// Macro-tile (ti,tj), tj>=ti; block covers rows [ti*256,+256) x cols
// [tj*256+ch*128,+128). B staged once (32 KB), conflict-free XOR layout
// (measured 0 conflicts): chunk (col,c) -> unit (col>>4)*256+c*16+((col&15)^c).
// Wave owns 32 rows (afrag[2][4]=32 VGPRs); 8 nt-tiles of 16 cols.
// Row partials -> zpartR[row][tj2] (tj2 = tj*2+ch). Col partials (off-diag
// only) -> cpart LDS combine -> atomicAdd zcol[col].
__global__ __launch_bounds__(512) void
contrastive_main(const ushort* __restrict__ Ebf, float* __restrict__ zpartR,
                 float* __restrict__ zcol, const float* __restrict__ emb,
                 const int* __restrict__ labels, float* __restrict__ gsum,
                 int* __restrict__ gcnt) {
    __shared__ __align__(16) ushort Bs[2048 * 8];     // 32 KB (2048 16B units)
    __shared__ float cpart[8][128];                   // 4 KB
    const int tid  = threadIdx.x;
    const int lane = tid & 63;
    const int wid  = tid >> 6;                        // 0..7
    const int quad = lane >> 4;
    const int l16  = lane & 15;

    if (blockIdx.x >= 1056) {
        // ---- class sums: 256 blocks x 8 waves, 1 class per wave ----
        int* labs = (int*)&Bs[0];                     // alias the 32 KB region
#pragma unroll
        for (int it = 0; it < 4; ++it)
            ((int4*)labs)[it * 512 + tid] = ((const int4*)labels)[it * 512 + tid];
        __syncthreads();

        const int c = (blockIdx.x - 1056) * 8 + wid;  // class id [0,2048)
        float2 acc = {0.f, 0.f};
        int cnt = 0;
        int nl = labs[lane];
        for (int j0 = 0; j0 < BATCH; j0 += 64) {
            int cur = nl;
            int nidx = j0 + 64 < BATCH ? j0 + 64 : 0;
            nl = labs[nidx + lane];
            unsigned long long m = __ballot(cur == c);
            cnt += __popcll(m);
            while (m) {
                int j = __ffsll(m) - 1;
                m &= m - 1;
                float2 v = *(const float2*)(emb + (size_t)(j0 + j) * DIMK + lane * 2);
                acc.x += v.x; acc.y += v.y;
            }
        }
        *(float2*)(gsum + (size_t)c * DIMK + lane * 2) = acc;
        if (lane == 0) gcnt[c] = cnt;
        return;
    }

    // ---- tile path ----
    // XCD-aware bijective swizzle: 1056 = 8 * 132; (bid&7) == XCD gets the
    // contiguous tt range [x*132, x*132+132) (R16: FETCH 8->6 MB).
    const int bid = blockIdx.x;
    const int tt  = (bid & 7) * 132 + (bid >> 3);

    // tt -> (ti, tj, ch)
    int b = tt >> 1;
    const int ch = tt & 1;
    int ti = 0;
    while (b >= 32 - ti) { b -= 32 - ti; ++ti; }
    const int tj  = ti + b;
    const int tj2 = tj * 2 + ch;
    const int row_base = ti * 256 + wid * 32;
    const int col_base = tj * 256 + ch * 128;

    // A-fragments for this wave's 32 rows (register-resident), from L2.
    bf16x8 afrag[2][4];
#pragma unroll
    for (int mt = 0; mt < 2; ++mt)
#pragma unroll
        for (int kk = 0; kk < 4; ++kk)
            afrag[mt][kk] = *(const bf16x8*)(Ebf + (size_t)(row_base + mt * 16 + l16) * DIMK
                                             + kk * 32 + quad * 8);

    // Stage 128 cols: 2048 16B chunks; thread t handles chunk f = it*512+t:
    // col = f>>4, c = f&15; global read coalesced (16 lanes = 256B of one col);
    // LDS write at swizzled unit (col>>4)*256 + c*16 + ((col&15)^c).
#pragma unroll
    for (int it = 0; it < 4; ++it) {
        int f   = it * 512 + tid;
        int col = f >> 4;
        int c   = f & 15;
        uint4 v = *(const uint4*)(Ebf + (size_t)(col_base + col) * DIMK + c * 8);
        *(uint4*)&Bs[((col >> 4) * 256 + c * 16 + ((col & 15) ^ c)) * 8] = v;
    }
    __syncthreads();

    float zacc[8];
#pragma unroll
    for (int s = 0; s < 8; ++s) zacc[s] = 0.f;

    for (int nt = 0; nt < 8; ++nt) {
        bf16x8 bfrag[4];
#pragma unroll
        for (int kk = 0; kk < 4; ++kk) {
            const int c2 = kk * 4 + quad;
            bfrag[kk] = *(const bf16x8*)&Bs[(nt * 256 + c2 * 16 + (l16 ^ c2)) * 8];
        }

        float csum = 0.f;
#pragma unroll
        for (int mt = 0; mt < 2; ++mt) {
            f32x4 c = {0.f, 0.f, 0.f, 0.f};
#pragma unroll
            for (int kk = 0; kk < 4; ++kk)
                c = __builtin_amdgcn_mfma_f32_16x16x32_bf16(afrag[mt][kk], bfrag[kk], c, 0, 0, 0);
#pragma unroll
            for (int r = 0; r < 4; ++r) {
                float e = __builtin_amdgcn_exp2f(__builtin_fmaf(c[r], K1, -K2));
                zacc[mt * 4 + r] += e;
                csum += e;
            }
        }
        // col partial for col (nt*16 + l16) over this wave's 32 rows
        csum += __shfl_xor(csum, 16, 64);
        csum += __shfl_xor(csum, 32, 64);
        if (quad == 0) cpart[wid][nt * 16 + l16] = csum;
    }

    // Row partials: reduce each row-slot over the 16 lanes sharing the row;
    // store transposed: zpartR[row][tj2] (fin1 reads 256B/row coalesced).
#pragma unroll
    for (int s = 0; s < 8; ++s) {
        float z = zacc[s];
#pragma unroll
        for (int m = 1; m <= 8; m <<= 1) z += __shfl_xor(z, m, 64);
        if (l16 == 0) {
            int row = row_base + (s >> 2) * 16 + quad * 4 + (s & 3);
            zpartR[(size_t)row * 64 + tj2] = z;
        }
    }

    // Col partials: combine the 8 waves, one distributed atomic per column.
    __syncthreads();
    if (ti != tj && tid < 128) {
        float s = cpart[0][tid] + cpart[1][tid] + cpart[2][tid] + cpart[3][tid]
                + cpart[4][tid] + cpart[5][tid] + cpart[6][tid] + cpart[7][tid];
        atomicAdd(&zcol[col_base + tid], s);
    }
}

// ---------------------------------------------------------------------------
// Finalize 1: 512 blocks x 256 (4 waves); each wave processes 4 rows.
// Per row: lane l covers dims 2l,2l+1; Z gather is zpartR[r][lane] — 256B
// contiguous (written only for tj2 >= 2*(r>>8): mask, no pre-zeroing);
// zcol[r] added after the butterfly (broadcast load).
__global__ __launch_bounds__(256) void
finalize1(const float* __restrict__ emb, const ushort* __restrict__ Ebf,
          const int* __restrict__ labels, const float* __restrict__ gsum,
          const int* __restrict__ gcnt, const float* __restrict__ zpartR,
          const float* __restrict__ zcol,
          float* __restrict__ bpart, int* __restrict__ bcnt) {
    __shared__ float sf[4];
    __shared__ int   si[4];
    const int lane = threadIdx.x & 63;
    const int wid  = threadIdx.x >> 6;

    float wsum = 0.f;
    int   wcnt = 0;
#pragma unroll
    for (int it = 0; it < 4; ++it) {
        const int r   = blockIdx.x * 16 + wid * 4 + it;
        const int lab = labels[r];
        const int P   = gcnt[lab] - 1;
        const int tp2 = (r >> 8) * 2;         // first valid tj2 for this row

        float2 ev = *(const float2*)(emb  + (size_t)r   * DIMK + lane * 2);
        float2 gv = *(const float2*)(gsum + (size_t)lab * DIMK + lane * 2);
        unsigned bb = *(const unsigned*)(Ebf + (size_t)r * DIMK + lane * 2);
        float b0 = bf2f((unsigned short)(bb & 0xFFFF));
        float b1 = bf2f((unsigned short)(bb >> 16));

        float dotg = ev.x * gv.x + ev.y * gv.y;
        float ssd  = ev.x * ev.x + ev.y * ev.y;
        float sdbf = b0 * b0 + b1 * b1;
        float Z = 0.f;
        if (lane >= tp2) Z = zpartR[(size_t)r * 64 + lane];

#pragma unroll
        for (int m = 1; m <= 32; m <<= 1) {
            dotg += __shfl_xor(dotg, m, 64);
            ssd  += __shfl_xor(ssd,  m, 64);
            sdbf += __shfl_xor(sdbf, m, 64);
            Z    += __shfl_xor(Z,    m, 64);
        }
        Z += zcol[r];                                                // below-diag cols
        Z -= __builtin_amdgcn_exp2f(__builtin_fmaf(sdbf, K1, -K2));  // remove diagonal

        const bool has = (P > 0);
        wsum += has ? ((dotg - ssd) * INV_T / (float)P - MSUB - __logf(Z)) : 0.f;
        wcnt += has ? 1 : 0;
    }

    if (lane == 0) { sf[wid] = wsum; si[wid] = wcnt; }
    __syncthreads();
    if (threadIdx.x == 0) {
        bpart[blockIdx.x] = sf[0] + sf[1] + sf[2] + sf[3];
        bcnt [blockIdx.x] = si[0] + si[1] + si[2] + si[3];
    }
}

// ---------------------------------------------------------------------------
// Finalize 2: reduce 512 block partials -> scalar loss. 1 block x 256.
__global__ __launch_bounds__(256) void
finalize2(const float* __restrict__ bpart, const int* __restrict__ bcnt,
          float* __restrict__ out) {
    __shared__ float sf[4];
    __shared__ int   si[4];
    const int t = threadIdx.x;
    float v = 0.f; int c = 0;
#pragma unroll
    for (int k = 0; k < 2; ++k) {
        v += bpart[t + k * 256];
        c += bcnt [t + k * 256];
    }
#pragma unroll
    for (int m = 1; m <= 32; m <<= 1) {
        v += __shfl_xor(v, m, 64);
        c += __shfl_xor(c, m, 64);
    }
    if ((t & 63) == 0) { sf[t >> 6] = v; si[t >> 6] = c; }
    __syncthreads();
    if (t == 0) {
        float tot = sf[0] + sf[1] + sf[2] + sf[3];
        int cc = si[0] + si[1] + si[2] + si[3];
        out[0] = -tot / (float)(cc > 0 ? cc : 1);
    }
}

extern "C" void kernel_launch(void* const* d_in, const int* in_sizes, int n_in,
                              void* d_out, int out_size, void* d_ws, size_t ws_size,
                              hipStream_t stream) {
    const float* emb  = (const float*)d_in[0];
    const int* labels = (const int*)d_in[1];
    float* out        = (float*)d_out;

    char* ws = (char*)d_ws;
    ushort* Ebf    = (ushort*)ws;                         // 2 MB  (8192*128*2)
    float*  zpartR = (float*)(ws + (2u << 20));           // 2 MB  ([8192][64] f32)
    float*  zcol   = (float*)(ws + (4u << 20));           // 32 KB (8192*4)
    float*  gsum   = (float*)(ws + (5u << 20));           // 1 MB  (2048*128*4)
    int*    gcnt   = (int*)  (ws + (6u << 20));           // 8 KB
    float*  bpart  = (float*)(ws + (6u << 20) + 8192);    // 8 KB
    int*    bcnt   = (int*)  (ws + (6u << 20) + 16384);   // 8 KB

    prep_kernel<<<1024, 256, 0, stream>>>(emb, Ebf, (float4*)zcol);
    contrastive_main<<<1312, 512, 0, stream>>>(Ebf, zpartR, zcol,
                                               emb, labels, gsum, gcnt);
    finalize1<<<512, 256, 0, stream>>>(emb, Ebf, labels, gsum, gcnt, zpartR, zcol,
                                       bpart, bcnt);
    finalize2<<<1, 256, 0, stream>>>(bpart, bcnt, out);
}